// Round 1
// baseline (242.188 us; speedup 1.0000x reference)
//
#include <hip/hip_runtime.h>
#include <math.h>

#define NN 500
#define TT 48
#define NT 24000   // NN*TT

// ---------- kernel 0a: row sums of s ----------
__global__ void k_srow(const float* __restrict__ s, float* __restrict__ srow) {
    int r = blockIdx.x;
    int l = threadIdx.x;
    float v = 0.f;
    for (int j = l; j < NN; j += 64) v += s[r * NN + j];
    #pragma unroll
    for (int o = 32; o; o >>= 1) v += __shfl_xor(v, o);
    if (l == 0) srow[r] = v;
}

// ---------- kernel 0b: rowsum[k] = (47 - k/500)*0.8 + srow[k%500] ----------
__global__ void k_rs(const float* __restrict__ srow, float* __restrict__ rs) {
    int k = blockIdx.x * 256 + threadIdx.x;
    if (k < NT) {
        int i = k / NN;
        int v = k - i * NN;
        rs[k] = (float)(TT - 1 - i) * 0.8f + srow[v];
    }
}

// ---------- kernel 1: per-(b,c) softmax over 24000, folded to per-n sums ----------
// grid = B*C = 4096 blocks, 512 threads. Thread n owns the 48 elements of node n.
__launch_bounds__(512, 4)
__global__ void k_p1(const float* __restrict__ x, const float* __restrict__ rs,
                     float* __restrict__ xws) {
    int bc = blockIdx.x;
    int n = threadIdx.x;
    bool act = (n < NN);

    float y[48];
    float m = -3.0e38f;
    if (act) {
        const float4* xp = (const float4*)(x + (size_t)bc * NT + n * TT);
        const float4* rp = (const float4*)(rs + n * TT);
        #pragma unroll
        for (int j = 0; j < 12; j++) {
            float4 xv = xp[j];
            float4 rv = rp[j];
            float4 yv;
            yv.x = fmaxf(xv.x * rv.x * 0.125f, 0.f);
            yv.y = fmaxf(xv.y * rv.y * 0.125f, 0.f);
            yv.z = fmaxf(xv.z * rv.z * 0.125f, 0.f);
            yv.w = fmaxf(xv.w * rv.w * 0.125f, 0.f);
            y[4 * j + 0] = yv.x; y[4 * j + 1] = yv.y;
            y[4 * j + 2] = yv.z; y[4 * j + 3] = yv.w;
            m = fmaxf(m, fmaxf(fmaxf(yv.x, yv.y), fmaxf(yv.z, yv.w)));
        }
    }

    // block max over 8 waves
    #pragma unroll
    for (int o = 32; o; o >>= 1) m = fmaxf(m, __shfl_xor(m, o));
    __shared__ float redm[8], reds[8];
    int wid = n >> 6, lane = n & 63;
    if (lane == 0) redm[wid] = m;
    __syncthreads();
    float M = redm[0];
    #pragma unroll
    for (int i = 1; i < 8; i++) M = fmaxf(M, redm[i]);

    // per-n numerator = this thread's exp-sum; block sum = Z
    float sn = 0.f;
    if (act) {
        #pragma unroll
        for (int i = 0; i < 48; i++) sn += __expf(y[i] - M);
    }
    float zz = sn;
    #pragma unroll
    for (int o = 32; o; o >>= 1) zz += __shfl_xor(zz, o);
    if (lane == 0) reds[wid] = zz;
    __syncthreads();
    float Z = 0.f;
    #pragma unroll
    for (int i = 0; i < 8; i++) Z += reds[i];

    if (act) xws[(size_t)bc * NN + n] = sn / Z;
}

// ---------- kernel 2: gram (X^T X over C=64) fused with row softmax ----------
// grid = (8 row-tiles of 64, 64 batches), 512 threads = 8 waves.
// Wave rt owns rows r0..r0+7 entirely (all 500 cols inside the wave) ->
// row softmax is pure shfl, output written exactly once.
__launch_bounds__(512, 2)
__global__ void k_p2(const float* __restrict__ xws, float* __restrict__ out) {
    __shared__ __align__(16) float Xs[64 * NN + 64];
    int b = blockIdx.y;
    int rt8 = blockIdx.x;   // 0..7
    int tid = threadIdx.x;

    // stage X_b [64][500] into LDS (8000 float4)
    const float4* src4 = (const float4*)(xws + (size_t)b * 64 * NN);
    #pragma unroll
    for (int i = 0; i < 16; i++) {
        int idx = tid + i * 512;
        if (idx < 8000) ((float4*)Xs)[idx] = src4[idx];
    }
    if (tid < 64) Xs[64 * NN + tid] = 0.f;   // zero the guard pad
    __syncthreads();

    int rt = tid >> 6, cx = tid & 63;
    int r0 = rt8 * 64 + rt * 8;
    int cb0 = cx * 4, cb1 = cx * 4 + 256;

    float acc[8][8];
    #pragma unroll
    for (int i = 0; i < 8; i++)
        #pragma unroll
        for (int j = 0; j < 8; j++) acc[i][j] = 0.f;

    #pragma unroll 4
    for (int c = 0; c < 64; c++) {
        const float* row = Xs + c * NN;
        float4 a0 = *(const float4*)(row + r0);       // broadcast (uniform addr)
        float4 a1 = *(const float4*)(row + r0 + 4);
        float4 b0 = *(const float4*)(row + cb0);      // lanes contiguous 16B
        float4 b1 = *(const float4*)(row + cb1);
        float av[8] = {a0.x, a0.y, a0.z, a0.w, a1.x, a1.y, a1.z, a1.w};
        float bv[8] = {b0.x, b0.y, b0.z, b0.w, b1.x, b1.y, b1.z, b1.w};
        #pragma unroll
        for (int i = 0; i < 8; i++)
            #pragma unroll
            for (int j = 0; j < 8; j++)
                acc[i][j] = fmaf(av[i], bv[j], acc[i][j]);
    }

    bool c1v = (cx <= 60);          // chunk1 cols 256+4cx.. valid iff cx<=60
    size_t ob = (size_t)b * (NN * NN);
    #pragma unroll 1
    for (int ri = 0; ri < 8; ri++) {
        int r = r0 + ri;
        if (r >= NN) break;         // wave-uniform
        float u[8];
        #pragma unroll
        for (int j = 0; j < 8; j++) u[j] = fmaxf(acc[ri][j], 0.f) * 0.125f;
        float mx = fmaxf(fmaxf(u[0], u[1]), fmaxf(u[2], u[3]));
        if (c1v) mx = fmaxf(mx, fmaxf(fmaxf(u[4], u[5]), fmaxf(u[6], u[7])));
        #pragma unroll
        for (int o = 32; o; o >>= 1) mx = fmaxf(mx, __shfl_xor(mx, o));

        float e[8];
        float es = 0.f;
        #pragma unroll
        for (int j = 0; j < 4; j++) { e[j] = __expf(u[j] - mx); es += e[j]; }
        if (c1v) {
            #pragma unroll
            for (int j = 4; j < 8; j++) { e[j] = __expf(u[j] - mx); es += e[j]; }
        }
        #pragma unroll
        for (int o = 32; o; o >>= 1) es += __shfl_xor(es, o);
        float inv = 1.f / es;

        float4 w0 = make_float4(e[0] * inv, e[1] * inv, e[2] * inv, e[3] * inv);
        *(float4*)(out + ob + (size_t)r * NN + cb0) = w0;
        if (c1v) {
            float4 w1 = make_float4(e[4] * inv, e[5] * inv, e[6] * inv, e[7] * inv);
            *(float4*)(out + ob + (size_t)r * NN + cb1) = w1;
        }
    }
}

extern "C" void kernel_launch(void* const* d_in, const int* in_sizes, int n_in,
                              void* d_out, int out_size, void* d_ws, size_t ws_size,
                              hipStream_t stream) {
    const float* x = (const float*)d_in[0];   // [64,64,500,48]
    const float* s = (const float*)d_in[1];   // [500,500]
    float* out = (float*)d_out;               // [64,500,500]
    float* wsf = (float*)d_ws;

    float* srow = wsf;             // 500 floats
    float* rs   = wsf + 1024;      // 24000 floats
    float* xws  = wsf + 32768;     // 64*64*500 = 2,048,000 floats (~8.2 MB)

    k_srow<<<NN, 64, 0, stream>>>(s, srow);
    k_rs<<<(NT + 255) / 256, 256, 0, stream>>>(srow, rs);
    k_p1<<<64 * 64, 512, 0, stream>>>(x, rs, xws);
    dim3 g2(8, 64);
    k_p2<<<g2, 512, 0, stream>>>(xws, out);
}

// Round 2
// 169.259 us; speedup vs baseline: 1.4309x; 1.4309x over previous
//
#include <hip/hip_runtime.h>
#include <math.h>

#define NN 500
#define TT 48
#define NT 24000   // NN*TT
#define NF4 6000   // NT/4

// ---------- kernel 0a: row sums of s ----------
__global__ void k_srow(const float* __restrict__ s, float* __restrict__ srow) {
    int r = blockIdx.x;
    int l = threadIdx.x;
    float v = 0.f;
    for (int j = l; j < NN; j += 64) v += s[r * NN + j];
    #pragma unroll
    for (int o = 32; o; o >>= 1) v += __shfl_xor(v, o);
    if (l == 0) srow[r] = v;
}

// ---------- kernel 0b: rowsum[k] = (47 - k/500)*0.8 + srow[k%500] ----------
__global__ void k_rs(const float* __restrict__ srow, float* __restrict__ rs) {
    int k = blockIdx.x * 256 + threadIdx.x;
    if (k < NT) {
        int i = k / NN;
        int v = k - i * NN;
        rs[k] = (float)(TT - 1 - i) * 0.8f + srow[v];
    }
}

// ---------- kernel 1: per-(b,c) softmax over 24000 folded to per-n sums ----------
// grid = B*C = 4096 blocks, 512 threads (8 waves).
// Wave w owns nodes [64w, 64w+64) = float4 range [768w, 768w+768): lane l loads
// f = 768w + 64i + l  (fully coalesced, 1 KB per wave instruction).
// Per-float4 exp-sums are regrouped via LDS so thread n gets node n's numerator.
__launch_bounds__(512, 4)
__global__ void k_p1(const float* __restrict__ x, const float* __restrict__ rs,
                     float* __restrict__ xws) {
    __shared__ float p[6144];          // per-float4 exp partial sums (f-indexed)
    __shared__ float redm[8], reds[8];
    int bc = blockIdx.x;
    int tid = threadIdx.x;
    int w = tid >> 6, l = tid & 63;
    int f0 = w * 768 + l;

    const float4* xp = (const float4*)x + (size_t)bc * NF4;
    const float4* rp = (const float4*)rs;

    float y[48];
    float m = 0.f;                     // relu output >= 0, so 0 is a safe identity
    #pragma unroll
    for (int i = 0; i < 12; i++) {
        int f = f0 + i * 64;
        float4 xv = make_float4(0.f, 0.f, 0.f, 0.f);
        float4 rv = xv;
        if (f < NF4) { xv = xp[f]; rv = rp[f]; }
        float4 yv;
        yv.x = fmaxf(xv.x * rv.x * 0.125f, 0.f);
        yv.y = fmaxf(xv.y * rv.y * 0.125f, 0.f);
        yv.z = fmaxf(xv.z * rv.z * 0.125f, 0.f);
        yv.w = fmaxf(xv.w * rv.w * 0.125f, 0.f);
        y[4 * i + 0] = yv.x; y[4 * i + 1] = yv.y;
        y[4 * i + 2] = yv.z; y[4 * i + 3] = yv.w;
        m = fmaxf(m, fmaxf(fmaxf(yv.x, yv.y), fmaxf(yv.z, yv.w)));
    }

    // block max over 8 waves
    #pragma unroll
    for (int o = 32; o; o >>= 1) m = fmaxf(m, __shfl_xor(m, o));
    if (l == 0) redm[w] = m;
    __syncthreads();
    float M = redm[0];
    #pragma unroll
    for (int i = 1; i < 8; i++) M = fmaxf(M, redm[i]);

    // exp, per-float4 partial sums -> LDS (conflict-free writes), lane total -> Z
    float tot = 0.f;
    #pragma unroll
    for (int i = 0; i < 12; i++) {
        int f = f0 + i * 64;
        float sf = 0.f;
        if (f < NF4) {
            sf = __expf(y[4 * i + 0] - M) + __expf(y[4 * i + 1] - M)
               + __expf(y[4 * i + 2] - M) + __expf(y[4 * i + 3] - M);
        }
        p[f0 + i * 64] = sf;
        tot += sf;
    }
    #pragma unroll
    for (int o = 32; o; o >>= 1) tot += __shfl_xor(tot, o);
    if (l == 0) reds[w] = tot;
    __syncthreads();
    float Z = 0.f;
    #pragma unroll
    for (int i = 0; i < 8; i++) Z += reds[i];

    // thread n gathers node n's 12 consecutive partials
    if (tid < NN) {
        const float* pp = p + tid * 12;
        float sn = 0.f;
        #pragma unroll
        for (int j = 0; j < 12; j++) sn += pp[j];
        xws[(size_t)bc * NN + tid] = sn / Z;
    }
}

// ---------- kernel 2: gram (X^T X over C=64) fused with row softmax ----------
// grid = (8 row-tiles of 64, 64 batches), 512 threads = 8 waves.
// Wave rt owns rows r0..r0+7 entirely (all 500 cols inside the wave) ->
// row softmax is pure shfl, output written exactly once.
__launch_bounds__(512, 2)
__global__ void k_p2(const float* __restrict__ xws, float* __restrict__ out) {
    __shared__ __align__(16) float Xs[64 * NN + 64];
    int b = blockIdx.y;
    int rt8 = blockIdx.x;   // 0..7
    int tid = threadIdx.x;

    // stage X_b [64][500] into LDS (8000 float4)
    const float4* src4 = (const float4*)(xws + (size_t)b * 64 * NN);
    #pragma unroll
    for (int i = 0; i < 16; i++) {
        int idx = tid + i * 512;
        if (idx < 8000) ((float4*)Xs)[idx] = src4[idx];
    }
    if (tid < 64) Xs[64 * NN + tid] = 0.f;   // zero the guard pad
    __syncthreads();

    int rt = tid >> 6, cx = tid & 63;
    int r0 = rt8 * 64 + rt * 8;
    int cb0 = cx * 4, cb1 = cx * 4 + 256;

    float acc[8][8];
    #pragma unroll
    for (int i = 0; i < 8; i++)
        #pragma unroll
        for (int j = 0; j < 8; j++) acc[i][j] = 0.f;

    #pragma unroll 4
    for (int c = 0; c < 64; c++) {
        const float* row = Xs + c * NN;
        float4 a0 = *(const float4*)(row + r0);       // broadcast (uniform addr)
        float4 a1 = *(const float4*)(row + r0 + 4);
        float4 b0 = *(const float4*)(row + cb0);      // lanes contiguous 16B
        float4 b1 = *(const float4*)(row + cb1);
        float av[8] = {a0.x, a0.y, a0.z, a0.w, a1.x, a1.y, a1.z, a1.w};
        float bv[8] = {b0.x, b0.y, b0.z, b0.w, b1.x, b1.y, b1.z, b1.w};
        #pragma unroll
        for (int i = 0; i < 8; i++)
            #pragma unroll
            for (int j = 0; j < 8; j++)
                acc[i][j] = fmaf(av[i], bv[j], acc[i][j]);
    }

    bool c1v = (cx <= 60);          // chunk1 cols 256+4cx.. valid iff cx<=60
    size_t ob = (size_t)b * (NN * NN);
    #pragma unroll 1
    for (int ri = 0; ri < 8; ri++) {
        int r = r0 + ri;
        if (r >= NN) break;         // wave-uniform
        float u[8];
        #pragma unroll
        for (int j = 0; j < 8; j++) u[j] = fmaxf(acc[ri][j], 0.f) * 0.125f;
        float mx = fmaxf(fmaxf(u[0], u[1]), fmaxf(u[2], u[3]));
        if (c1v) mx = fmaxf(mx, fmaxf(fmaxf(u[4], u[5]), fmaxf(u[6], u[7])));
        #pragma unroll
        for (int o = 32; o; o >>= 1) mx = fmaxf(mx, __shfl_xor(mx, o));

        float e[8];
        float es = 0.f;
        #pragma unroll
        for (int j = 0; j < 4; j++) { e[j] = __expf(u[j] - mx); es += e[j]; }
        if (c1v) {
            #pragma unroll
            for (int j = 4; j < 8; j++) { e[j] = __expf(u[j] - mx); es += e[j]; }
        }
        #pragma unroll
        for (int o = 32; o; o >>= 1) es += __shfl_xor(es, o);
        float inv = 1.f / es;

        float4 w0 = make_float4(e[0] * inv, e[1] * inv, e[2] * inv, e[3] * inv);
        *(float4*)(out + ob + (size_t)r * NN + cb0) = w0;
        if (c1v) {
            float4 w1 = make_float4(e[4] * inv, e[5] * inv, e[6] * inv, e[7] * inv);
            *(float4*)(out + ob + (size_t)r * NN + cb1) = w1;
        }
    }
}

extern "C" void kernel_launch(void* const* d_in, const int* in_sizes, int n_in,
                              void* d_out, int out_size, void* d_ws, size_t ws_size,
                              hipStream_t stream) {
    const float* x = (const float*)d_in[0];   // [64,64,500,48]
    const float* s = (const float*)d_in[1];   // [500,500]
    float* out = (float*)d_out;               // [64,500,500]
    float* wsf = (float*)d_ws;

    float* srow = wsf;             // 500 floats
    float* rs   = wsf + 1024;      // 24000 floats
    float* xws  = wsf + 32768;     // 64*64*500 = 2,048,000 floats (~8.2 MB)

    k_srow<<<NN, 64, 0, stream>>>(s, srow);
    k_rs<<<(NT + 255) / 256, 256, 0, stream>>>(srow, rs);
    k_p1<<<64 * 64, 512, 0, stream>>>(x, rs, xws);
    dim3 g2(8, 64);
    k_p2<<<g2, 512, 0, stream>>>(xws, out);
}